// Round 13
// baseline (382.017 us; speedup 1.0000x reference)
//
#include <hip/hip_runtime.h>
#include <hip/hip_bf16.h>
#include <hip/hip_fp16.h>
#include <math.h>

// Problem dims (fixed by reference)
#define B_  32
#define T_  512
#define F_  4096
#define H_  128
#define G4H 512           // 4*H
#define NCLS 3            // NUM_CLASSES + 1
#define M_  (B_ * T_)     // 16384 rows
#define KSTEPS 128        // F_/32

typedef _Float16 f16x8 __attribute__((ext_vector_type(8)));
typedef _Float16 f16x4 __attribute__((ext_vector_type(4)));
typedef float    f32x4 __attribute__((ext_vector_type(4)));

// ---------------------------------------------------------------------------
// Kernel 0b: Wk [F,4H] fp32 -> btK fp16, K-MAJOR tiles with baked-in group
// swizzle: group g (8 halves) of column n stored at half-offset
//   n*32 + ((g ^ ((n>>1)&3)) << 3)
// ---------------------------------------------------------------------------
__global__ __launch_bounds__(256) void cvt_wkT(
    const float* __restrict__ Wk, _Float16* __restrict__ btK)
{
    __shared__ float ls[64][65];
    const int k0 = blockIdx.x * 64;
    const int n0 = blockIdx.y * 64;
    const int tid = threadIdx.x;

    {
        int r  = tid >> 4;
        int c4 = (tid & 15) * 4;
        #pragma unroll
        for (int p = 0; p < 4; ++p) {
            float4 v = *reinterpret_cast<const float4*>(
                &Wk[(size_t)(k0 + r + p * 16) * G4H + n0 + c4]);
            ls[r + p * 16][c4 + 0] = v.x;
            ls[r + p * 16][c4 + 1] = v.y;
            ls[r + p * 16][c4 + 2] = v.z;
            ls[r + p * 16][c4 + 3] = v.w;
        }
    }
    __syncthreads();
    {
        int rn = tid >> 2;            // n within tile 0..63
        int ck = (tid & 3) * 16;      // k within tile 0,16,32,48
        f16x8 h0, h1;
        #pragma unroll
        for (int j = 0; j < 8; ++j) {
            h0[j] = (_Float16)ls[ck + j][rn];
            h1[j] = (_Float16)ls[ck + 8 + j][rn];
        }
        const int n    = n0 + rn;
        const int kg   = k0 + ck;
        const int kblk = kg >> 5;
        const int kk   = kg & 31;           // 0 or 16
        const int g0   = kk >> 3;           // 0 or 2
        const int sw   = (n >> 1) & 3;
        _Float16* base = btK + (size_t)kblk * (512 * 32) + (size_t)n * 32;
        *reinterpret_cast<f16x8*>(base + ((g0 ^ sw) << 3))       = h0;
        *reinterpret_cast<f16x8*>(base + (((g0 + 1) ^ sw) << 3)) = h1;
    }
}

// ---------------------------------------------------------------------------
// Kernel 0c: Wr [H,4H] fp32 -> wrT [4H,H] fp16 (transpose). grid (2, 8).
// ---------------------------------------------------------------------------
__global__ __launch_bounds__(256) void cvt_wrT(
    const float* __restrict__ Wr, _Float16* __restrict__ wrT)
{
    __shared__ float ls[64][65];
    const int k0 = blockIdx.x * 64;
    const int n0 = blockIdx.y * 64;
    const int tid = threadIdx.x;
    {
        int r  = tid >> 4;
        int c4 = (tid & 15) * 4;
        #pragma unroll
        for (int p = 0; p < 4; ++p) {
            float4 v = *reinterpret_cast<const float4*>(
                &Wr[(size_t)(k0 + r + p * 16) * G4H + n0 + c4]);
            ls[r + p * 16][c4 + 0] = v.x;
            ls[r + p * 16][c4 + 1] = v.y;
            ls[r + p * 16][c4 + 2] = v.z;
            ls[r + p * 16][c4 + 3] = v.w;
        }
    }
    __syncthreads();
    {
        int rn = tid >> 2;
        int ck = (tid & 3) * 16;
        f16x8 h0, h1;
        #pragma unroll
        for (int j = 0; j < 8; ++j) {
            h0[j] = (_Float16)ls[ck + j][rn];
            h1[j] = (_Float16)ls[ck + 8 + j][rn];
        }
        _Float16* dst = &wrT[(size_t)(n0 + rn) * H_ + k0 + ck];
        *reinterpret_cast<f16x8*>(dst)     = h0;
        *reinterpret_cast<f16x8*>(dst + 8) = h1;
    }
}

// Light producer-consumer barrier: LDS-drain only, no vmcnt drain.
__device__ __forceinline__ void lds_barrier() {
    asm volatile("s_waitcnt lgkmcnt(0)" ::: "memory");
    __builtin_amdgcn_s_barrier();
    asm volatile("" ::: "memory");
}

// ---------------------------------------------------------------------------
// Kernel 1: FUSED z = f16(x) @ Wk + b.
// R28 = R21 gemm body (per-step lds_barrier, B double-buffered in REGISTERS,
// A LDS double-buffer, BN=256, 8 waves, 2 blk/CU) with planar z store.
// Pairwise-subtraction ledger (same-lstm pairs only, after discovering the
// rocprof-vs-timed bias): gemm-R21 ~138.5 < gemm-R23-4group ~155 <
// gemm-glds ~179. R24's "grouped beats glds by 24" conclusion used a bad
// pair; this round is the clean A/B of R21-gemm vs R23-gemm at fixed lstm.
// ---------------------------------------------------------------------------
__global__ __launch_bounds__(512, 4) void gemm_fused(
    const float* __restrict__ x, const _Float16* __restrict__ btK,
    const float* __restrict__ bias, float* __restrict__ z)
{
    __shared__ __align__(16) _Float16 As[2][64 * 32];    // 8 KB total

    const int tid = threadIdx.x;
    const int w   = tid >> 6;
    const int l   = tid & 63;
    const int fr  = l & 15;
    const int q   = l >> 4;

    // 512 blocks = 8 xcd * (32 m-pairs * 2 n); siblings adjacent on one XCD
    const int bid   = blockIdx.x;
    const int xcd   = bid & 7;
    const int idx   = bid >> 3;
    const int mt    = xcd * 32 + (idx >> 1);
    const int ntile = idx & 1;
    const int m0    = mt * 64;
    const int n0    = ntile * 256;

    // x staging: thread -> (row ar, cols hc..hc+3), swizzled f16 LDS layout
    const int ar = tid >> 3;
    const int hc = (tid & 7) * 4;
    const int abyte = ((((hc >> 3) ^ ((ar >> 1) & 3)) << 4) | ((hc << 1) & 15));
    const float* xrow = x + (size_t)(m0 + ar) * F_ + hc;

    // per-lane B pointers (swizzle baked into btK storage)
    const int nA = n0 + w * 32 + fr;        // j = 0 column
    const int nB = nA + 16;                 // j = 1 column
    const _Float16* bp0 = btK + (size_t)nA * 32 + ((q ^ ((nA >> 1) & 3)) << 3);
    const _Float16* bp1 = btK + (size_t)nB * 32 + ((q ^ ((nB >> 1) & 3)) << 3);

    #define LOADB(t, bfv)                                                     \
    {                                                                         \
        bfv[0] = *reinterpret_cast<const f16x8*>(bp0 + (size_t)(t) * 16384);  \
        bfv[1] = *reinterpret_cast<const f16x8*>(bp1 + (size_t)(t) * 16384);  \
    }

    #define LOADX(t) (*reinterpret_cast<const float4*>(xrow + (size_t)(t) * 32))

    #define WRITE_A(v, buf)                                                   \
    {                                                                         \
        f16x4 hh; hh[0] = (_Float16)v.x; hh[1] = (_Float16)v.y;               \
        hh[2] = (_Float16)v.z; hh[3] = (_Float16)v.w;                         \
        *reinterpret_cast<f16x4*>(                                            \
            reinterpret_cast<char*>(&As[buf][0]) + ar * 64 + abyte) = hh;     \
    }

    #define COMPUTE(buf, bfv)                                                 \
    {                                                                         \
        f16x8 af[4];                                                          \
        _Pragma("unroll")                                                     \
        for (int i = 0; i < 4; ++i) {                                         \
            int r   = i * 16 + fr;                                            \
            int off = r * 64 + ((q ^ ((r >> 1) & 3)) << 4);                   \
            af[i] = *reinterpret_cast<const f16x8*>(                          \
                reinterpret_cast<const char*>(&As[buf][0]) + off);            \
        }                                                                     \
        _Pragma("unroll")                                                     \
        for (int i = 0; i < 4; ++i)                                           \
            _Pragma("unroll")                                                 \
            for (int j = 0; j < 2; ++j)                                       \
                acc[i][j] = __builtin_amdgcn_mfma_f32_16x16x32_f16(           \
                    af[i], bfv[j], acc[i][j], 0, 0, 0);                       \
    }

    f32x4 acc[4][2] = {};
    f16x8 bfA[2], bfB[2];
    float4 xa, xb;

    // prologue
    xa = LOADX(0); xb = LOADX(1);
    LOADB(0, bfA) LOADB(1, bfB)
    WRITE_A(xa, 0)                    // compiler waits xa (counted vmcnt)
    lds_barrier();                    // A(0) visible; B loads stay in flight

    for (int t = 0; t < 126; t += 2) {
        // iter t (buf 0, bfA)
        xa = LOADX(t + 2);
        WRITE_A(xb, 1)                // stage A(t+1); waits xb only
        COMPUTE(0, bfA)
        LOADB(t + 2, bfA)             // refill after use (2-step lead)
        lds_barrier();
        // iter t+1 (buf 1, bfB)
        xb = LOADX(t + 3);
        WRITE_A(xa, 0)                // stage A(t+2)
        COMPUTE(1, bfB)
        LOADB(t + 3, bfB)
        lds_barrier();
    }
    // t = 126 (buf 0, bfA holds B(126))
    WRITE_A(xb, 1)                    // stage A(127), xb = x(127)
    COMPUTE(0, bfA)
    lds_barrier();
    // t = 127 (buf 1, bfB holds B(127))
    COMPUTE(1, bfB)

    #undef LOADB
    #undef LOADX
    #undef WRITE_A
    #undef COMPUTE

    // planar z store: z[row][nn], nn = gate*128 + ch (fr-contiguous 64B bursts)
    #pragma unroll
    for (int j = 0; j < 2; ++j) {
        const int nn = n0 + w * 32 + j * 16 + fr;
        const float bj = bias[nn];
        #pragma unroll
        for (int i = 0; i < 4; ++i)
            #pragma unroll
            for (int r = 0; r < 4; ++r)
                z[(size_t)(m0 + i * 16 + q * 4 + r) * G4H + nn]
                    = acc[i][j][r] + bj;
    }
}

// ---------------------------------------------------------------------------
// Kernel 2: MFMA LSTM recurrence — R27 merged 512-step body VERBATIM
// (planar z, raw v_exp/v_rcp gates, direct h store). Timed ~187us ≈ its
// structural floor (620cy MFMA-pipe/step + VALU tail + sync).
// ---------------------------------------------------------------------------
__device__ __forceinline__ float sig_f(float x) {
    return __builtin_amdgcn_rcpf(
        1.0f + __builtin_amdgcn_exp2f(-1.442695040888963f * x));
}
__device__ __forceinline__ float tanh_f(float x) {
    return 1.0f - 2.0f * __builtin_amdgcn_rcpf(
        1.0f + __builtin_amdgcn_exp2f(2.885390081777927f * x));
}

__global__ __launch_bounds__(512, 2) void lstm_mfma(
    const float* __restrict__ z,       // [B*T, 512] planar
    const _Float16* __restrict__ wrT,  // [4H, H] = Wr^T fp16
    float* __restrict__ hs)            // [B, T, H] fp32
{
    const int b    = blockIdx.x;
    const int tid  = threadIdx.x;
    const int w    = tid >> 6;
    const int lane = tid & 63;
    const int l15  = lane & 15;
    const int q    = lane >> 4;
    const int jj   = w * 16 + l15;

    __shared__ __align__(16) _Float16 hA[2][128];

    f16x8 bf[4][4];
    #pragma unroll
    for (int g = 0; g < 4; ++g)
        #pragma unroll
        for (int kf = 0; kf < 4; ++kf)
            bf[g][kf] = *reinterpret_cast<const f16x8*>(
                &wrT[(size_t)(g * H_ + jj) * H_ + kf * 32 + q * 8]);

    float cstate = 0.f;
    if (tid < 128) reinterpret_cast<unsigned int*>(hA)[tid] = 0u;

    const float* zq    = z  + (size_t)b * T_ * G4H + jj;   // + t*512 + g*128
    float*       hbase = hs + (size_t)b * T_ * H_;

    const f32x4 zero4 = {0.f, 0.f, 0.f, 0.f};

    #define LOADZ(t, d)                                                       \
    {                                                                         \
        int zo = (((t) & (T_ - 1)) << 9);                                     \
        d.x = zq[zo];       d.y = zq[zo + 128];                               \
        d.z = zq[zo + 256]; d.w = zq[zo + 384];                               \
    }

    float4 zP0, zP1, zP2, zP3;
    LOADZ(0, zP0) LOADZ(1, zP1) LOADZ(2, zP2) LOADZ(3, zP3)

    __syncthreads();

    #define LSTM_STEP(t, CUR, ZZ)                                             \
    {                                                                         \
        f16x8 af0 = *reinterpret_cast<const f16x8*>(&hA[CUR][0 * 32 + q * 8]);\
        f16x8 af1 = *reinterpret_cast<const f16x8*>(&hA[CUR][1 * 32 + q * 8]);\
        f16x8 af2 = *reinterpret_cast<const f16x8*>(&hA[CUR][2 * 32 + q * 8]);\
        f16x8 af3 = *reinterpret_cast<const f16x8*>(&hA[CUR][3 * 32 + q * 8]);\
        float zt0_ = ZZ.x, zt1_ = ZZ.y, zt2_ = ZZ.z, zt3_ = ZZ.w;             \
        LOADZ((t) + 4, ZZ)                                                    \
        float gv[4];                                                          \
        _Pragma("unroll")                                                     \
        for (int g = 0; g < 4; ++g) {                                         \
            f32x4 aA = __builtin_amdgcn_mfma_f32_16x16x32_f16(                \
                af0, bf[g][0], zero4, 0, 0, 0);                               \
            aA = __builtin_amdgcn_mfma_f32_16x16x32_f16(                      \
                af1, bf[g][1], aA, 0, 0, 0);                                  \
            f32x4 aB = __builtin_amdgcn_mfma_f32_16x16x32_f16(                \
                af2, bf[g][2], zero4, 0, 0, 0);                               \
            aB = __builtin_amdgcn_mfma_f32_16x16x32_f16(                      \
                af3, bf[g][3], aB, 0, 0, 0);                                  \
            gv[g] = aA[0] + aB[0];                                            \
        }                                                                     \
        float iv = sig_f(gv[0] + zt0_);                                       \
        float fv = sig_f(gv[1] + zt1_);                                       \
        float cc = tanh_f(gv[2] + zt2_);                                      \
        float ov = sig_f(gv[3] + zt3_);                                       \
        cstate = fv * cstate + iv * cc;                                       \
        float h = ov * tanh_f(cstate);                                        \
        if (q == 0) {                                                         \
            hA[CUR ^ 1][jj] = (_Float16)h;                                    \
            hbase[((t) << 7) + jj] = h;                                       \
        }                                                                     \
        lds_barrier();                                                        \
    }

    for (int t = 0; t < T_; t += 4) {
        LSTM_STEP(t,     0, zP0)
        LSTM_STEP(t + 1, 1, zP1)
        LSTM_STEP(t + 2, 0, zP2)
        LSTM_STEP(t + 3, 1, zP3)
    }
    #undef LSTM_STEP
    #undef LOADZ
}

// ---------------------------------------------------------------------------
// Kernel 3: out = hs @ Wd + bd
// ---------------------------------------------------------------------------
__global__ __launch_bounds__(256) void dense_out(
    const float* __restrict__ hs, const float* __restrict__ Wd,
    const float* __restrict__ bd, float* __restrict__ out)
{
    int idx = blockIdx.x * 256 + threadIdx.x;
    if (idx >= B_ * T_ * NCLS) return;
    int cls = idx % NCLS;
    int row = idx / NCLS;
    const float* h = hs + (size_t)row * H_;
    float acc = bd[cls];
    #pragma unroll 8
    for (int k = 0; k < H_; ++k) acc += h[k] * Wd[k * NCLS + cls];
    out[idx] = acc;
}

// ---------------------------------------------------------------------------
extern "C" void kernel_launch(void* const* d_in, const int* in_sizes, int n_in,
                              void* d_out, int out_size, void* d_ws, size_t ws_size,
                              hipStream_t stream)
{
    const float* x  = (const float*)d_in[0];
    const float* Wk = (const float*)d_in[1];
    const float* Wr = (const float*)d_in[2];
    const float* b  = (const float*)d_in[3];
    const float* Wd = (const float*)d_in[4];
    const float* bd = (const float*)d_in[5];
    float* out = (float*)d_out;

    float*     z   = (float*)d_ws;                       // [M, 512] fp32 planar
    float*     hs  = z + (size_t)M_ * G4H;               // [M, H]  fp32
    _Float16*  btK = (_Float16*)(hs + (size_t)M_ * H_);  // k-major swizzled, 4 MB
    _Float16*  wrT = btK + (size_t)G4H * F_;             // [4H, H] fp16

    cvt_wkT<<<dim3(F_ / 64, G4H / 64), 256, 0, stream>>>(Wk, btK);
    cvt_wrT<<<dim3(H_ / 64, G4H / 64), 256, 0, stream>>>(Wr, wrT);
    gemm_fused<<<512, 512, 0, stream>>>(x, btK, b, z);
    lstm_mfma<<<B_, 512, 0, stream>>>(z, wrT, hs);
    int total = B_ * T_ * NCLS;
    dense_out<<<(total + 255) / 256, 256, 0, stream>>>(hs, Wd, bd, out);
}

// Round 14
// 350.729 us; speedup vs baseline: 1.0892x; 1.0892x over previous
//
#include <hip/hip_runtime.h>
#include <hip/hip_bf16.h>
#include <hip/hip_fp16.h>
#include <math.h>

// Problem dims (fixed by reference)
#define B_  32
#define T_  512
#define F_  4096
#define H_  128
#define G4H 512           // 4*H
#define NCLS 3            // NUM_CLASSES + 1
#define M_  (B_ * T_)     // 16384 rows
#define KSTEPS 128        // F_/32

typedef _Float16 f16x8 __attribute__((ext_vector_type(8)));
typedef _Float16 f16x4 __attribute__((ext_vector_type(4)));
typedef float    f32x4 __attribute__((ext_vector_type(4)));

// ---------------------------------------------------------------------------
// Kernel 0b: Wk [F,4H] fp32 -> btK fp16, K-MAJOR tiles with baked-in group
// swizzle: group g (8 halves) of column n stored at half-offset
//   n*32 + ((g ^ ((n>>1)&3)) << 3)
// ---------------------------------------------------------------------------
__global__ __launch_bounds__(256) void cvt_wkT(
    const float* __restrict__ Wk, _Float16* __restrict__ btK)
{
    __shared__ float ls[64][65];
    const int k0 = blockIdx.x * 64;
    const int n0 = blockIdx.y * 64;
    const int tid = threadIdx.x;

    {
        int r  = tid >> 4;
        int c4 = (tid & 15) * 4;
        #pragma unroll
        for (int p = 0; p < 4; ++p) {
            float4 v = *reinterpret_cast<const float4*>(
                &Wk[(size_t)(k0 + r + p * 16) * G4H + n0 + c4]);
            ls[r + p * 16][c4 + 0] = v.x;
            ls[r + p * 16][c4 + 1] = v.y;
            ls[r + p * 16][c4 + 2] = v.z;
            ls[r + p * 16][c4 + 3] = v.w;
        }
    }
    __syncthreads();
    {
        int rn = tid >> 2;            // n within tile 0..63
        int ck = (tid & 3) * 16;      // k within tile 0,16,32,48
        f16x8 h0, h1;
        #pragma unroll
        for (int j = 0; j < 8; ++j) {
            h0[j] = (_Float16)ls[ck + j][rn];
            h1[j] = (_Float16)ls[ck + 8 + j][rn];
        }
        const int n    = n0 + rn;
        const int kg   = k0 + ck;
        const int kblk = kg >> 5;
        const int kk   = kg & 31;           // 0 or 16
        const int g0   = kk >> 3;           // 0 or 2
        const int sw   = (n >> 1) & 3;
        _Float16* base = btK + (size_t)kblk * (512 * 32) + (size_t)n * 32;
        *reinterpret_cast<f16x8*>(base + ((g0 ^ sw) << 3))       = h0;
        *reinterpret_cast<f16x8*>(base + (((g0 + 1) ^ sw) << 3)) = h1;
    }
}

// ---------------------------------------------------------------------------
// Kernel 0c: Wr [H,4H] fp32 -> wrT [4H,H] fp16 (transpose). grid (2, 8).
// ---------------------------------------------------------------------------
__global__ __launch_bounds__(256) void cvt_wrT(
    const float* __restrict__ Wr, _Float16* __restrict__ wrT)
{
    __shared__ float ls[64][65];
    const int k0 = blockIdx.x * 64;
    const int n0 = blockIdx.y * 64;
    const int tid = threadIdx.x;
    {
        int r  = tid >> 4;
        int c4 = (tid & 15) * 4;
        #pragma unroll
        for (int p = 0; p < 4; ++p) {
            float4 v = *reinterpret_cast<const float4*>(
                &Wr[(size_t)(k0 + r + p * 16) * G4H + n0 + c4]);
            ls[r + p * 16][c4 + 0] = v.x;
            ls[r + p * 16][c4 + 1] = v.y;
            ls[r + p * 16][c4 + 2] = v.z;
            ls[r + p * 16][c4 + 3] = v.w;
        }
    }
    __syncthreads();
    {
        int rn = tid >> 2;
        int ck = (tid & 3) * 16;
        f16x8 h0, h1;
        #pragma unroll
        for (int j = 0; j < 8; ++j) {
            h0[j] = (_Float16)ls[ck + j][rn];
            h1[j] = (_Float16)ls[ck + 8 + j][rn];
        }
        _Float16* dst = &wrT[(size_t)(n0 + rn) * H_ + k0 + ck];
        *reinterpret_cast<f16x8*>(dst)     = h0;
        *reinterpret_cast<f16x8*>(dst + 8) = h1;
    }
}

// Light producer-consumer barrier: LDS-drain only, no vmcnt drain.
__device__ __forceinline__ void lds_barrier() {
    asm volatile("s_waitcnt lgkmcnt(0)" ::: "memory");
    __builtin_amdgcn_s_barrier();
    asm volatile("" ::: "memory");
}

// ---------------------------------------------------------------------------
// Kernel 1: FUSED z = f16(x) @ Wk + b.  == R23 SOURCE VERBATIM ==
// Best-measured gemm (clean A/B R27 vs R28: beats per-step B-regs by 31us).
// B in regs 2-deep, 4-step barrier groups, planar z store [row][gate*128+ch].
// ---------------------------------------------------------------------------
__global__ __launch_bounds__(512, 4) void gemm_fused(
    const float* __restrict__ x, const _Float16* __restrict__ btK,
    const float* __restrict__ bias, float* __restrict__ z)
{
    __shared__ __align__(16) _Float16 As[2][4][64 * 32];   // 32 KB

    const int tid = threadIdx.x;
    const int w   = tid >> 6;
    const int l   = tid & 63;
    const int fr  = l & 15;
    const int q   = l >> 4;

    // 512 blocks = 8 xcd * (32 m-pairs * 2 n); siblings adjacent on one XCD
    const int bid   = blockIdx.x;
    const int xcd   = bid & 7;
    const int idx   = bid >> 3;
    const int mt    = xcd * 32 + (idx >> 1);
    const int ntile = idx & 1;
    const int m0    = mt * 64;
    const int n0    = ntile * 256;

    // x staging: thread -> (row ar, cols hc..hc+3), swizzled f16 LDS layout
    const int ar = tid >> 3;
    const int hc = (tid & 7) * 4;
    const int abyte = ((((hc >> 3) ^ ((ar >> 1) & 3)) << 4) | ((hc << 1) & 15));
    const float* xrow = x + (size_t)(m0 + ar) * F_ + hc;

    // per-lane B pointers (swizzle baked into btK storage)
    const int nA = n0 + w * 32 + fr;        // j = 0 column
    const int nB = nA + 16;                 // j = 1 column
    const _Float16* bp0 = btK + (size_t)nA * 32 + ((q ^ ((nA >> 1) & 3)) << 3);
    const _Float16* bp1 = btK + (size_t)nB * 32 + ((q ^ ((nB >> 1) & 3)) << 3);

    #define LOADB(t, bfv)                                                     \
    {                                                                         \
        bfv[0] = *reinterpret_cast<const f16x8*>(bp0 + (size_t)(t) * 16384);  \
        bfv[1] = *reinterpret_cast<const f16x8*>(bp1 + (size_t)(t) * 16384);  \
    }

    #define LOADX(t) (*reinterpret_cast<const float4*>(xrow + (size_t)(t) * 32))

    #define WRITE_A(v, G, s)                                                  \
    {                                                                         \
        f16x4 hh; hh[0] = (_Float16)v.x; hh[1] = (_Float16)v.y;               \
        hh[2] = (_Float16)v.z; hh[3] = (_Float16)v.w;                         \
        *reinterpret_cast<f16x4*>(                                            \
            reinterpret_cast<char*>(&As[G][s][0]) + ar * 64 + abyte) = hh;    \
    }

    #define COMPUTE(G, s, bfv)                                                \
    {                                                                         \
        f16x8 af[4];                                                          \
        _Pragma("unroll")                                                     \
        for (int i = 0; i < 4; ++i) {                                         \
            int r   = i * 16 + fr;                                            \
            int off = r * 64 + ((q ^ ((r >> 1) & 3)) << 4);                   \
            af[i] = *reinterpret_cast<const f16x8*>(                          \
                reinterpret_cast<const char*>(&As[G][s][0]) + off);           \
        }                                                                     \
        _Pragma("unroll")                                                     \
        for (int i = 0; i < 4; ++i)                                           \
            _Pragma("unroll")                                                 \
            for (int j = 0; j < 2; ++j)                                       \
                acc[i][j] = __builtin_amdgcn_mfma_f32_16x16x32_f16(           \
                    af[i], bfv[j], acc[i][j], 0, 0, 0);                       \
    }

    // One group = 4 K-steps computed from As[G], staging group g+1 into
    // As[G^1], issuing x for group g+2. One barrier per group.
    #define GROUP(t0, G)                                                      \
    {                                                                         \
        WRITE_A(xq0, G ^ 1, 0) WRITE_A(xq1, G ^ 1, 1)                         \
        WRITE_A(xq2, G ^ 1, 2) WRITE_A(xq3, G ^ 1, 3)                         \
        xq0 = LOADX((t0) + 8);  xq1 = LOADX((t0) + 9);                        \
        xq2 = LOADX((t0) + 10); xq3 = LOADX((t0) + 11);                       \
        COMPUTE(G, 0, bfA) LOADB((t0) + 2, bfA)                               \
        COMPUTE(G, 1, bfB) LOADB((t0) + 3, bfB)                               \
        COMPUTE(G, 2, bfA) LOADB((t0) + 4, bfA)                               \
        COMPUTE(G, 3, bfB) LOADB((t0) + 5, bfB)                               \
        lds_barrier();                                                        \
    }

    f32x4 acc[4][2] = {};
    f16x8 bfA[2], bfB[2];
    float4 xq0, xq1, xq2, xq3;

    // prologue: stage group 0, preload x for group 1, B(0),B(1)
    xq0 = LOADX(0); xq1 = LOADX(1); xq2 = LOADX(2); xq3 = LOADX(3);
    WRITE_A(xq0, 0, 0) WRITE_A(xq1, 0, 1) WRITE_A(xq2, 0, 2) WRITE_A(xq3, 0, 3)
    xq0 = LOADX(4); xq1 = LOADX(5); xq2 = LOADX(6); xq3 = LOADX(7);
    LOADB(0, bfA) LOADB(1, bfB)
    lds_barrier();

    // groups 0..29 (t0 = 0..116): full steady state (x issue reaches t=127)
    for (int gg = 0; gg < 30; gg += 2) {
        const int t0 = gg * 4;
        GROUP(t0, 0)
        GROUP(t0 + 4, 1)
    }
    // group 30 (t0=120, G=0): stage group 31, no more x issue
    {
        WRITE_A(xq0, 1, 0) WRITE_A(xq1, 1, 1) WRITE_A(xq2, 1, 2) WRITE_A(xq3, 1, 3)
        COMPUTE(0, 0, bfA) LOADB(122, bfA)
        COMPUTE(0, 1, bfB) LOADB(123, bfB)
        COMPUTE(0, 2, bfA) LOADB(124, bfA)
        COMPUTE(0, 3, bfB) LOADB(125, bfB)
        lds_barrier();
    }
    // group 31 (t0=124, G=1): final
    {
        COMPUTE(1, 0, bfA) LOADB(126, bfA)
        COMPUTE(1, 1, bfB) LOADB(127, bfB)
        COMPUTE(1, 2, bfA)
        COMPUTE(1, 3, bfB)
    }

    #undef LOADB
    #undef LOADX
    #undef WRITE_A
    #undef COMPUTE
    #undef GROUP

    // planar z store: z[row][nn] (gate = nn>>7, ch = nn&127)
    #pragma unroll
    for (int j = 0; j < 2; ++j) {
        const int nn = n0 + w * 32 + j * 16 + fr;
        const float bj = bias[nn];
        #pragma unroll
        for (int i = 0; i < 4; ++i)
            #pragma unroll
            for (int r = 0; r < 4; ++r)
                z[(size_t)(m0 + i * 16 + q * 4 + r) * G4H + nn]
                    = acc[i][j][r] + bj;
    }
}

// ---------------------------------------------------------------------------
// Kernel 2: MFMA LSTM recurrence — merged 512-step dispatch (planar z, raw
// v_exp/v_rcp gates, direct h store). ~187us timed, at its structural floor.
// ---------------------------------------------------------------------------
__device__ __forceinline__ float sig_f(float x) {
    return __builtin_amdgcn_rcpf(
        1.0f + __builtin_amdgcn_exp2f(-1.442695040888963f * x));
}
__device__ __forceinline__ float tanh_f(float x) {
    return 1.0f - 2.0f * __builtin_amdgcn_rcpf(
        1.0f + __builtin_amdgcn_exp2f(2.885390081777927f * x));
}

__global__ __launch_bounds__(512, 2) void lstm_mfma(
    const float* __restrict__ z,       // [B*T, 512] planar
    const _Float16* __restrict__ wrT,  // [4H, H] = Wr^T fp16
    float* __restrict__ hs)            // [B, T, H] fp32
{
    const int b    = blockIdx.x;
    const int tid  = threadIdx.x;
    const int w    = tid >> 6;
    const int lane = tid & 63;
    const int l15  = lane & 15;
    const int q    = lane >> 4;
    const int jj   = w * 16 + l15;

    __shared__ __align__(16) _Float16 hA[2][128];

    f16x8 bf[4][4];
    #pragma unroll
    for (int g = 0; g < 4; ++g)
        #pragma unroll
        for (int kf = 0; kf < 4; ++kf)
            bf[g][kf] = *reinterpret_cast<const f16x8*>(
                &wrT[(size_t)(g * H_ + jj) * H_ + kf * 32 + q * 8]);

    float cstate = 0.f;
    if (tid < 128) reinterpret_cast<unsigned int*>(hA)[tid] = 0u;

    const float* zq    = z  + (size_t)b * T_ * G4H + jj;   // + t*512 + g*128
    float*       hbase = hs + (size_t)b * T_ * H_;

    const f32x4 zero4 = {0.f, 0.f, 0.f, 0.f};

    #define LOADZ(t, d)                                                       \
    {                                                                         \
        int zo = (((t) & (T_ - 1)) << 9);                                     \
        d.x = zq[zo];       d.y = zq[zo + 128];                               \
        d.z = zq[zo + 256]; d.w = zq[zo + 384];                               \
    }

    float4 zP0, zP1, zP2, zP3;
    LOADZ(0, zP0) LOADZ(1, zP1) LOADZ(2, zP2) LOADZ(3, zP3)

    __syncthreads();

    #define LSTM_STEP(t, CUR, ZZ)                                             \
    {                                                                         \
        f16x8 af0 = *reinterpret_cast<const f16x8*>(&hA[CUR][0 * 32 + q * 8]);\
        f16x8 af1 = *reinterpret_cast<const f16x8*>(&hA[CUR][1 * 32 + q * 8]);\
        f16x8 af2 = *reinterpret_cast<const f16x8*>(&hA[CUR][2 * 32 + q * 8]);\
        f16x8 af3 = *reinterpret_cast<const f16x8*>(&hA[CUR][3 * 32 + q * 8]);\
        float zt0_ = ZZ.x, zt1_ = ZZ.y, zt2_ = ZZ.z, zt3_ = ZZ.w;             \
        LOADZ((t) + 4, ZZ)                                                    \
        float gv[4];                                                          \
        _Pragma("unroll")                                                     \
        for (int g = 0; g < 4; ++g) {                                         \
            f32x4 aA = __builtin_amdgcn_mfma_f32_16x16x32_f16(                \
                af0, bf[g][0], zero4, 0, 0, 0);                               \
            aA = __builtin_amdgcn_mfma_f32_16x16x32_f16(                      \
                af1, bf[g][1], aA, 0, 0, 0);                                  \
            f32x4 aB = __builtin_amdgcn_mfma_f32_16x16x32_f16(                \
                af2, bf[g][2], zero4, 0, 0, 0);                               \
            aB = __builtin_amdgcn_mfma_f32_16x16x32_f16(                      \
                af3, bf[g][3], aB, 0, 0, 0);                                  \
            gv[g] = aA[0] + aB[0];                                            \
        }                                                                     \
        float iv = sig_f(gv[0] + zt0_);                                       \
        float fv = sig_f(gv[1] + zt1_);                                       \
        float cc = tanh_f(gv[2] + zt2_);                                      \
        float ov = sig_f(gv[3] + zt3_);                                       \
        cstate = fv * cstate + iv * cc;                                       \
        float h = ov * tanh_f(cstate);                                        \
        if (q == 0) {                                                         \
            hA[CUR ^ 1][jj] = (_Float16)h;                                    \
            hbase[((t) << 7) + jj] = h;                                       \
        }                                                                     \
        lds_barrier();                                                        \
    }

    for (int t = 0; t < T_; t += 4) {
        LSTM_STEP(t,     0, zP0)
        LSTM_STEP(t + 1, 1, zP1)
        LSTM_STEP(t + 2, 0, zP2)
        LSTM_STEP(t + 3, 1, zP3)
    }
    #undef LSTM_STEP
    #undef LOADZ
}

// ---------------------------------------------------------------------------
// Kernel 3: out = hs @ Wd + bd
// ---------------------------------------------------------------------------
__global__ __launch_bounds__(256) void dense_out(
    const float* __restrict__ hs, const float* __restrict__ Wd,
    const float* __restrict__ bd, float* __restrict__ out)
{
    int idx = blockIdx.x * 256 + threadIdx.x;
    if (idx >= B_ * T_ * NCLS) return;
    int cls = idx % NCLS;
    int row = idx / NCLS;
    const float* h = hs + (size_t)row * H_;
    float acc = bd[cls];
    #pragma unroll 8
    for (int k = 0; k < H_; ++k) acc += h[k] * Wd[k * NCLS + cls];
    out[idx] = acc;
}

// ---------------------------------------------------------------------------
extern "C" void kernel_launch(void* const* d_in, const int* in_sizes, int n_in,
                              void* d_out, int out_size, void* d_ws, size_t ws_size,
                              hipStream_t stream)
{
    const float* x  = (const float*)d_in[0];
    const float* Wk = (const float*)d_in[1];
    const float* Wr = (const float*)d_in[2];
    const float* b  = (const float*)d_in[3];
    const float* Wd = (const float*)d_in[4];
    const float* bd = (const float*)d_in[5];
    float* out = (float*)d_out;

    float*     z   = (float*)d_ws;                       // [M, 512] fp32 planar
    float*     hs  = z + (size_t)M_ * G4H;               // [M, H]  fp32
    _Float16*  btK = (_Float16*)(hs + (size_t)M_ * H_);  // k-major swizzled, 4 MB
    _Float16*  wrT = btK + (size_t)G4H * F_;             // [4H, H] fp16

    cvt_wkT<<<dim3(F_ / 64, G4H / 64), 256, 0, stream>>>(Wk, btK);
    cvt_wrT<<<dim3(H_ / 64, G4H / 64), 256, 0, stream>>>(Wr, wrT);
    gemm_fused<<<512, 512, 0, stream>>>(x, btK, b, z);
    lstm_mfma<<<B_, 512, 0, stream>>>(z, wrT, hs);
    int total = B_ * T_ * NCLS;
    dense_out<<<(total + 255) / 256, 256, 0, stream>>>(hs, Wd, bd, out);
}